// Round 7
// baseline (135.456 us; speedup 1.0000x reference)
//
#include <hip/hip_runtime.h>
#include <hip/hip_bf16.h>

// Geometry: B=32, Cin=128, Cout=256, H=W=56, K=3, pad=1, stride=1
// Implicit GEMM: M = B*H*Wpad(64), N = 256, K = 9 taps * 128 cin
//
// xpad layout (NHWC, swizzled): per (b,hh) a 16KB row-blob:
//   byte(w, c) = w*256 + ((c*2) ^ ((w&7)<<4)),  w in [0,64), c in [0,128)
// wt2 layout: per (r, kc) a 16KB blob = two 8KB nh-halves, 64 rows of 128B
//   pairing n and n+64: byte = nh*8192 + rr*128 + (((n>>6&1)*64 + k2) ^ ((rr&7)<<4))
// Swizzles are involutions; conv stages with global_load_lds (LINEAR dest)
// and reads with the same formula (rule #21).
//
// conv schedule (T3+T4+T5): A resident 96KB; B = 3-slot ring (3x16KB).
// Step s: waitcnt vmcnt(2) [stage s landed, s+1 in flight] -> raw s_barrier
// -> issue stage s+2 into slot (s+2)%3 [= (s-1)%3, readers done pre-barrier]
// -> ds_read frags -> setprio(1) 32 MFMA setprio(0). vmcnt never drains to 0.

typedef __attribute__((ext_vector_type(8))) __bf16 bf16x8;
typedef __attribute__((ext_vector_type(4))) float f32x4;
typedef __attribute__((ext_vector_type(8))) unsigned short u16x8;

#define WT2_ELEMS (9 * 4 * 2 * 4096)     // 294,912 u16 = 576 KB
#define XP_ELEMS  (32 * 58 * 8192)       // 15,204,352 u16 = ~30.4 MB

__device__ __forceinline__ void gload_lds16(const void* g, void* l) {
    __builtin_amdgcn_global_load_lds(
        (const __attribute__((address_space(1))) void*)g,
        (__attribute__((address_space(3))) void*)l, 16, 0, 0);
}

// ---- weight prep: w[cout][cin][3][3] - wz -> wt2 blobs (swizzle-baked) ----
__global__ void wprep_kernel(const float* __restrict__ w, const float* __restrict__ wzp,
                             unsigned short* __restrict__ wt2) {
    int t = blockIdx.x * 256 + threadIdx.x;      // < 294912
    int blobi = t >> 12;                         // (r*4+kc)*2 + nh
    int e = t & 4095;
    int byte = e * 2;
    int rr = byte >> 7;                          // row 0..63
    int slot = byte & 127;
    int us = slot ^ ((rr & 7) << 4);             // un-swizzle
    int hi = (us >> 6) & 1;
    int kl = (us & 63) >> 1;                     // k within chunk 0..31
    int nh = blobi & 1;
    int s  = blobi >> 1;
    int kc = s & 3, r = s >> 2;
    int n = nh * 128 + hi * 64 + rr;
    int k = kc * 32 + kl;
    float v = w[(size_t)n * 1152 + k * 9 + r] - *wzp;
    wt2[t] = (unsigned short)(__float_as_uint(v) >> 16);   // exact (small ints)
}

// ---- x prep: NCHW -> swizzled padded NHWC bf16 ----
__global__ void xprep_kernel(const float* __restrict__ x, const float* __restrict__ xzp,
                             unsigned short* __restrict__ xp) {
    int bhh = blockIdx.x;                        // b*58 + hh
    int b = bhh / 58, hh = bhh % 58;
    int t = threadIdx.x;
    char* blob = (char*)(xp + (size_t)bhh * 8192);
    if (hh == 0 || hh == 57) {
        u16x8 z = {0, 0, 0, 0, 0, 0, 0, 0};
#pragma unroll
        for (int i = 0; i < 4; ++i)
            *(u16x8*)(blob + (i * 256 + t) * 16) = z;
        return;
    }
    int h = hh - 1;
    float xz = *xzp;
    const float* xb = x + (size_t)b * 128 * 3136 + h * 56;   // + c*3136 + w
#pragma unroll
    for (int i = 0; i < 4; ++i) {
        int chunk = i * 256 + t;                 // 0..1023
        int byte = chunk * 16;
        int w = byte >> 8;                       // 0..63
        int slot = byte & 255;
        int c2 = slot ^ ((w & 7) << 4);          // un-swizzle -> source c
        int c0 = c2 >> 1;
        int wsrc = w - 1;
        bool valid = (unsigned)wsrc < 56u;
        u16x8 v;
#pragma unroll
        for (int j = 0; j < 8; ++j) {
            float f = valid ? (xb[(size_t)(c0 + j) * 3136 + wsrc] - xz) : 0.0f;
            v[j] = (unsigned short)(__float_as_uint(f) >> 16);
        }
        *(u16x8*)(blob + byte) = v;
    }
}

// ---- main conv ----
__global__ __launch_bounds__(512, 2)
void conv_kernel(const unsigned short* __restrict__ wt2,
                 const unsigned short* __restrict__ xp,
                 const float* __restrict__ bias,
                 const float* __restrict__ Mp,
                 const float* __restrict__ yzp,
                 float* __restrict__ out) {
    __shared__ __align__(1024) char smem[147456];    // A 96KB + B ring 3x16KB
    char* As = smem;
    char* Bs = smem + 98304;

    const int tid = threadIdx.x;
    const int lane = tid & 63;
    const int wid = tid >> 6;                        // 0..7
    const int l15 = lane & 15, lg = lane >> 4;
    const int wm = wid >> 2;                         // 0..1: which h-row pair
    const int wn = wid & 3;                          // 0..3: which 64-cout slice
    const int bx = blockIdx.x;                       // b*14 + h-group
    const int b = bx / 14;
    const int h0 = (bx % 14) * 4;                    // 4 output rows per block

    // ---- prologue: A = 6 row-blobs (96KB); B stages 0,1 into slots 0,1 ----
    const char* agbase = (const char*)xp + (size_t)(b * 58 + h0) * 16384;
    const char* wgbase = (const char*)wt2;
#pragma unroll
    for (int i = 0; i < 12; ++i) {
        int off = i * 8192 + wid * 1024;
        gload_lds16(agbase + off + lane * 16, As + off);
    }
#pragma unroll
    for (int t = 0; t < 2; ++t) {
        const char* src = wgbase + (size_t)t * 16384;
        char* dst = Bs + t * 16384;
        gload_lds16(src + wid * 1024 + lane * 16, dst + wid * 1024);
        gload_lds16(src + 8192 + wid * 1024 + lane * 16, dst + 8192 + wid * 1024);
    }

    f32x4 acc[8][4];
#pragma unroll
    for (int i = 0; i < 8; ++i)
#pragma unroll
        for (int j = 0; j < 4; ++j)
            acc[i][j] = (f32x4){0.f, 0.f, 0.f, 0.f};

#pragma unroll
    for (int kh = 0; kh < 3; ++kh) {
#pragma unroll
        for (int kw = 0; kw < 3; ++kw) {
#pragma unroll
            for (int kc = 0; kc < 4; ++kc) {
                const int sidx = (kh * 3 + kw) * 4 + kc;     // compile-time
                // wait: stage sidx complete (stage sidx+1 stays in flight)
                if (sidx == 35) {
                    asm volatile("s_waitcnt vmcnt(0)" ::: "memory");
                } else {
                    asm volatile("s_waitcnt vmcnt(2)" ::: "memory");
                }
                __builtin_amdgcn_s_barrier();
                // issue stage sidx+2 into slot (sidx+2)%3 (WAR-safe post-barrier)
                if (sidx + 2 <= 35) {
                    const char* src = wgbase + (size_t)(sidx + 2) * 16384;
                    char* dst = Bs + ((sidx + 2) % 3) * 16384;
                    gload_lds16(src + wid * 1024 + lane * 16, dst + wid * 1024);
                    gload_lds16(src + 8192 + wid * 1024 + lane * 16,
                                dst + 8192 + wid * 1024);
                }
                // B fragments (4 x 16n for this wave's 64-cout slice)
                const int bslot = (sidx % 3) * 16384;
                bf16x8 bfr[4];
#pragma unroll
                for (int fn = 0; fn < 4; ++fn) {
                    int rr = fn * 16 + l15;
                    int bbyte = bslot + (wn >> 1) * 8192 + rr * 128 +
                                (((wn & 1) * 64 + lg * 16) ^ ((rr & 7) << 4));
                    bfr[fn] = *(const bf16x8*)(Bs + bbyte);
                }
                // A fragments: 8 x 16m (2 h-rows x 64w), swizzled read
                bf16x8 afr[8];
#pragma unroll
                for (int fm = 0; fm < 8; ++fm) {
                    int w = (fm & 3) * 16 + l15 + kw;
                    int wc = w > 63 ? 63 : w;        // clamped lanes are dead outputs
                    int row = wm * 2 + (fm >> 2) + kh;
                    int abyte = row * 16384 + wc * 256 +
                                ((kc * 64 + lg * 16) ^ ((wc & 7) << 4));
                    afr[fm] = *(const bf16x8*)(As + abyte);
                }
                __builtin_amdgcn_s_setprio(1);
#pragma unroll
                for (int fm = 0; fm < 8; ++fm)
#pragma unroll
                    for (int fn = 0; fn < 4; ++fn)
                        acc[fm][fn] = __builtin_amdgcn_mfma_f32_16x16x32_bf16(
                            afr[fm], bfr[fn], acc[fm][fn], 0, 0, 0);
                __builtin_amdgcn_s_setprio(0);
            }
        }
    }

    // ---- epilogue: requantize + ReLU + round ----
    const float Mv = *Mp;
    const float yzv = *yzp;
#pragma unroll
    for (int fn = 0; fn < 4; ++fn) {
        const int cout = wn * 64 + fn * 16 + l15;
        const float bv = bias[cout];
#pragma unroll
        for (int fm = 0; fm < 8; ++fm) {
            const int h = h0 + wm * 2 + (fm >> 2);
            const size_t rowb = ((size_t)(b * 256 + cout) * 56 + h) * 56;
#pragma unroll
            for (int reg = 0; reg < 4; ++reg) {
                int w = (fm & 3) * 16 + lg * 4 + reg;
                if (w < 56) {
                    float v = (acc[fm][fn][reg] + bv) * Mv + yzv;
                    v = fmaxf(v, yzv);
                    out[rowb + w] = rintf(v);
                }
            }
        }
    }
}

extern "C" void kernel_launch(void* const* d_in, const int* in_sizes, int n_in,
                              void* d_out, int out_size, void* d_ws, size_t ws_size,
                              hipStream_t stream) {
    const float* x    = (const float*)d_in[0];
    const float* w    = (const float*)d_in[1];
    const float* bias = (const float*)d_in[2];
    const float* Mp   = (const float*)d_in[3];
    const float* xzp  = (const float*)d_in[4];
    const float* wzp  = (const float*)d_in[5];
    const float* yzp  = (const float*)d_in[6];
    float* out = (float*)d_out;

    unsigned short* wt2 = (unsigned short*)d_ws;           // 576 KB
    unsigned short* xp  = wt2 + WT2_ELEMS;                 // ~30.4 MB

    wprep_kernel<<<WT2_ELEMS / 256, 256, 0, stream>>>(w, wzp, wt2);
    xprep_kernel<<<32 * 58, 256, 0, stream>>>(x, xzp, xp);

    conv_kernel<<<32 * 14, 512, 0, stream>>>(wt2, xp, bias, Mp, yzp, out);
}

// Round 9
// 133.254 us; speedup vs baseline: 1.0165x; 1.0165x over previous
//
#include <hip/hip_runtime.h>
#include <hip/hip_bf16.h>

// Geometry: B=32, Cin=128, Cout=256, H=W=56, K=3, pad=1, stride=1
// Implicit GEMM: M = B*H*Wpad(64), N = 256, K = 9 taps * 128 cin
//
// xpad layout (NHWC, swizzled): per (b,hh) a 16KB row-blob:
//   byte(w, c) = w*256 + ((c*2) ^ ((w&7)<<4)),  w in [0,64), c in [0,128)
// wt2 layout: per (r, kc) a 16KB blob = two 8KB nh-halves, 64 rows of 128B
//   pairing n and n+64: byte = nh*8192 + rr*128 + (((n>>6&1)*64 + k2) ^ ((rr&7)<<4))
// Swizzles are involutions; conv stages with global_load_lds (LINEAR dest)
// and reads with the same formula (rule #21).
//
// conv schedule: A resident 96KB; B = 4-slot ring (4x16KB), ONE
// __syncthreads per 2 K-steps (group). Group g reads slots {2g,2g+1}%4,
// prefetches stages 2g+2,2g+3 into slots {2g+2,2g+3}%4 (disjoint -> no WAR
// race); group-end barrier's implicit vmcnt(0) drain makes them visible.
// Barrier-free 2-step region lets the compiler pipeline sub-1 ds_reads
// under sub-0 MFMAs. LDS = 96 + 64 = 160 KB (full pool, 1 block/CU).

typedef __attribute__((ext_vector_type(8))) __bf16 bf16x8;
typedef __attribute__((ext_vector_type(4))) float f32x4;
typedef __attribute__((ext_vector_type(8))) unsigned short u16x8;

#define WT2_ELEMS (9 * 4 * 2 * 4096)     // 294,912 u16 = 576 KB
#define XP_ELEMS  (32 * 58 * 8192)       // 15,204,352 u16 = ~30.4 MB

__device__ __forceinline__ void gload_lds16(const void* g, void* l) {
    __builtin_amdgcn_global_load_lds(
        (const __attribute__((address_space(1))) void*)g,
        (__attribute__((address_space(3))) void*)l, 16, 0, 0);
}

// ---- weight prep: w[cout][cin][3][3] - wz -> wt2 blobs (swizzle-baked) ----
__global__ void wprep_kernel(const float* __restrict__ w, const float* __restrict__ wzp,
                             unsigned short* __restrict__ wt2) {
    int t = blockIdx.x * 256 + threadIdx.x;      // < 294912
    int blobi = t >> 12;                         // (r*4+kc)*2 + nh
    int e = t & 4095;
    int byte = e * 2;
    int rr = byte >> 7;                          // row 0..63
    int slot = byte & 127;
    int us = slot ^ ((rr & 7) << 4);             // un-swizzle
    int hi = (us >> 6) & 1;
    int kl = (us & 63) >> 1;                     // k within chunk 0..31
    int nh = blobi & 1;
    int s  = blobi >> 1;
    int kc = s & 3, r = s >> 2;
    int n = nh * 128 + hi * 64 + rr;
    int k = kc * 32 + kl;
    float v = w[(size_t)n * 1152 + k * 9 + r] - *wzp;
    wt2[t] = (unsigned short)(__float_as_uint(v) >> 16);   // exact (small ints)
}

// ---- x prep: NCHW -> swizzled padded NHWC bf16 ----
__global__ void xprep_kernel(const float* __restrict__ x, const float* __restrict__ xzp,
                             unsigned short* __restrict__ xp) {
    int bhh = blockIdx.x;                        // b*58 + hh
    int b = bhh / 58, hh = bhh % 58;
    int t = threadIdx.x;
    char* blob = (char*)(xp + (size_t)bhh * 8192);
    if (hh == 0 || hh == 57) {
        u16x8 z = {0, 0, 0, 0, 0, 0, 0, 0};
#pragma unroll
        for (int i = 0; i < 4; ++i)
            *(u16x8*)(blob + (i * 256 + t) * 16) = z;
        return;
    }
    int h = hh - 1;
    float xz = *xzp;
    const float* xb = x + (size_t)b * 128 * 3136 + h * 56;   // + c*3136 + w
#pragma unroll
    for (int i = 0; i < 4; ++i) {
        int chunk = i * 256 + t;                 // 0..1023
        int byte = chunk * 16;
        int w = byte >> 8;                       // 0..63
        int slot = byte & 255;
        int c2 = slot ^ ((w & 7) << 4);          // un-swizzle -> source c
        int c0 = c2 >> 1;
        int wsrc = w - 1;
        bool valid = (unsigned)wsrc < 56u;
        u16x8 v;
#pragma unroll
        for (int j = 0; j < 8; ++j) {
            float f = valid ? (xb[(size_t)(c0 + j) * 3136 + wsrc] - xz) : 0.0f;
            v[j] = (unsigned short)(__float_as_uint(f) >> 16);
        }
        *(u16x8*)(blob + byte) = v;
    }
}

// ---- main conv ----
__global__ __launch_bounds__(512, 2)
void conv_kernel(const unsigned short* __restrict__ wt2,
                 const unsigned short* __restrict__ xp,
                 const float* __restrict__ bias,
                 const float* __restrict__ Mp,
                 const float* __restrict__ yzp,
                 float* __restrict__ out) {
    __shared__ __align__(1024) char smem[163840];    // A 96KB + B ring 4x16KB
    char* As = smem;
    char* Bs = smem + 98304;

    const int tid = threadIdx.x;
    const int lane = tid & 63;
    const int wid = tid >> 6;                        // 0..7
    const int l15 = lane & 15, lg = lane >> 4;
    const int wm = wid >> 2;                         // 0..1: which h-row pair
    const int wn = wid & 3;                          // 0..3: which 64-cout slice
    const int bx = blockIdx.x;                       // b*14 + h-group
    const int b = bx / 14;
    const int h0 = (bx % 14) * 4;                    // 4 output rows per block

    // ---- prologue: A = 6 row-blobs (96KB); B stages 0,1 into slots 0,1 ----
    const char* agbase = (const char*)xp + (size_t)(b * 58 + h0) * 16384;
    const char* wgbase = (const char*)wt2;
#pragma unroll
    for (int i = 0; i < 12; ++i) {
        int off = i * 8192 + wid * 1024;
        gload_lds16(agbase + off + lane * 16, As + off);
    }
#pragma unroll
    for (int t = 0; t < 2; ++t) {
        const char* src = wgbase + (size_t)t * 16384;
        char* dst = Bs + t * 16384;
        gload_lds16(src + wid * 1024 + lane * 16, dst + wid * 1024);
        gload_lds16(src + 8192 + wid * 1024 + lane * 16, dst + 8192 + wid * 1024);
    }

    f32x4 acc[8][4];
#pragma unroll
    for (int i = 0; i < 8; ++i)
#pragma unroll
        for (int j = 0; j < 4; ++j)
            acc[i][j] = (f32x4){0.f, 0.f, 0.f, 0.f};

    __syncthreads();                                 // A + B0,B1 staged

#pragma unroll
    for (int g = 0; g < 18; ++g) {                   // 18 groups x 2 K-steps
        // prefetch next group's stages into slots {2g+2,2g+3}%4
        // (disjoint from this group's read slots {2g,2g+1}%4)
#pragma unroll
        for (int pf = 0; pf < 2; ++pf) {
            const int st = 2 * g + 2 + pf;
            if (st <= 35) {
                const char* src = wgbase + (size_t)st * 16384;
                char* dst = Bs + (st & 3) * 16384;
                gload_lds16(src + wid * 1024 + lane * 16, dst + wid * 1024);
                gload_lds16(src + 8192 + wid * 1024 + lane * 16,
                            dst + 8192 + wid * 1024);
            }
        }
#pragma unroll
        for (int sub = 0; sub < 2; ++sub) {
            const int s = 2 * g + sub;               // compile-time
            const int kh = s / 12, kw = (s / 4) % 3, kc = s & 3;
            const int bslot = (s & 3) * 16384;
            // B fragments (4 x 16n for this wave's 64-cout slice)
            bf16x8 bfr[4];
#pragma unroll
            for (int fn = 0; fn < 4; ++fn) {
                int rr = fn * 16 + l15;
                int bbyte = bslot + (wn >> 1) * 8192 + rr * 128 +
                            (((wn & 1) * 64 + lg * 16) ^ ((rr & 7) << 4));
                bfr[fn] = *(const bf16x8*)(Bs + bbyte);
            }
            // A fragments: 8 x 16m (2 h-rows x 64w), swizzled read
#pragma unroll
            for (int fm = 0; fm < 8; ++fm) {
                int w = (fm & 3) * 16 + l15 + kw;
                int wc = w > 63 ? 63 : w;            // clamped lanes are dead outputs
                int row = wm * 2 + (fm >> 2) + kh;
                int abyte = row * 16384 + wc * 256 +
                            ((kc * 64 + lg * 16) ^ ((wc & 7) << 4));
                bf16x8 a = *(const bf16x8*)(As + abyte);
#pragma unroll
                for (int fn = 0; fn < 4; ++fn)
                    acc[fm][fn] = __builtin_amdgcn_mfma_f32_16x16x32_bf16(
                        a, bfr[fn], acc[fm][fn], 0, 0, 0);
            }
        }
        __syncthreads();                             // drain prefetch + WAR guard
    }

    // ---- epilogue: requantize + ReLU + round ----
    const float Mv = *Mp;
    const float yzv = *yzp;
#pragma unroll
    for (int fn = 0; fn < 4; ++fn) {
        const int cout = wn * 64 + fn * 16 + l15;
        const float bv = bias[cout];
#pragma unroll
        for (int fm = 0; fm < 8; ++fm) {
            const int h = h0 + wm * 2 + (fm >> 2);
            const size_t rowb = ((size_t)(b * 256 + cout) * 56 + h) * 56;
#pragma unroll
            for (int reg = 0; reg < 4; ++reg) {
                int w = (fm & 3) * 16 + lg * 4 + reg;
                if (w < 56) {
                    float v = (acc[fm][fn][reg] + bv) * Mv + yzv;
                    v = fmaxf(v, yzv);
                    out[rowb + w] = rintf(v);
                }
            }
        }
    }
}

extern "C" void kernel_launch(void* const* d_in, const int* in_sizes, int n_in,
                              void* d_out, int out_size, void* d_ws, size_t ws_size,
                              hipStream_t stream) {
    const float* x    = (const float*)d_in[0];
    const float* w    = (const float*)d_in[1];
    const float* bias = (const float*)d_in[2];
    const float* Mp   = (const float*)d_in[3];
    const float* xzp  = (const float*)d_in[4];
    const float* wzp  = (const float*)d_in[5];
    const float* yzp  = (const float*)d_in[6];
    float* out = (float*)d_out;

    unsigned short* wt2 = (unsigned short*)d_ws;           // 576 KB
    unsigned short* xp  = wt2 + WT2_ELEMS;                 // ~30.4 MB

    wprep_kernel<<<WT2_ELEMS / 256, 256, 0, stream>>>(w, wzp, wt2);
    xprep_kernel<<<32 * 58, 256, 0, stream>>>(x, xzp, xp);

    conv_kernel<<<32 * 14, 512, 0, stream>>>(wt2, xp, bias, Mp, yzp, out);
}

// Round 10
// 132.139 us; speedup vs baseline: 1.0251x; 1.0084x over previous
//
#include <hip/hip_runtime.h>
#include <hip/hip_bf16.h>

// Geometry: B=32, Cin=128, Cout=256, H=W=56, K=3, pad=1, stride=1
// Implicit GEMM: M = B*H*Wpad(64), N = 256, K = 9 taps * 128 cin
//
// xpad layout (NHWC, swizzled): per (b,hh) a 16KB row-blob:
//   byte(w, c) = w*256 + ((c*2) ^ ((w&7)<<4)),  w in [0,64), c in [0,128)
// wt2 layout: per (r, kc) a 16KB blob = two 8KB nh-halves, 64 rows of 128B
//   pairing n and n+64: byte = nh*8192 + rr*128 + (((n>>6&1)*64 + k2) ^ ((rr&7)<<4))
// Swizzles are involutions; conv stages with global_load_lds (LINEAR dest)
// and reads with the same formula (rule #21).
//
// conv schedule (R6 structure + read-before-prefetch reorder): A resident
// 96KB; B dbuf 2x16KB; per K-step: [all 12 ds_read frags] -> [issue next B
// prefetch] -> [32 MFMA] -> __syncthreads. Any compiler-conservative
// vmcnt wait before the reads now covers only the PREVIOUS step's gload
// (a full step old -> free); the barrier drain of this step's prefetch is
// covered by the MFMA burst.

typedef __attribute__((ext_vector_type(8))) __bf16 bf16x8;
typedef __attribute__((ext_vector_type(4))) float f32x4;
typedef __attribute__((ext_vector_type(8))) unsigned short u16x8;

#define WT2_ELEMS (9 * 4 * 2 * 4096)     // 294,912 u16 = 576 KB
#define XP_ELEMS  (32 * 58 * 8192)       // 15,204,352 u16 = ~30.4 MB

__device__ __forceinline__ void gload_lds16(const void* g, void* l) {
    __builtin_amdgcn_global_load_lds(
        (const __attribute__((address_space(1))) void*)g,
        (__attribute__((address_space(3))) void*)l, 16, 0, 0);
}

// ---- weight prep: w[cout][cin][3][3] - wz -> wt2 blobs (swizzle-baked) ----
__global__ void wprep_kernel(const float* __restrict__ w, const float* __restrict__ wzp,
                             unsigned short* __restrict__ wt2) {
    int t = blockIdx.x * 256 + threadIdx.x;      // < 294912
    int blobi = t >> 12;                         // (r*4+kc)*2 + nh
    int e = t & 4095;
    int byte = e * 2;
    int rr = byte >> 7;                          // row 0..63
    int slot = byte & 127;
    int us = slot ^ ((rr & 7) << 4);             // un-swizzle
    int hi = (us >> 6) & 1;
    int kl = (us & 63) >> 1;                     // k within chunk 0..31
    int nh = blobi & 1;
    int s  = blobi >> 1;
    int kc = s & 3, r = s >> 2;
    int n = nh * 128 + hi * 64 + rr;
    int k = kc * 32 + kl;
    float v = w[(size_t)n * 1152 + k * 9 + r] - *wzp;
    wt2[t] = (unsigned short)(__float_as_uint(v) >> 16);   // exact (small ints)
}

// ---- x prep: NCHW -> swizzled padded NHWC bf16 ----
__global__ void xprep_kernel(const float* __restrict__ x, const float* __restrict__ xzp,
                             unsigned short* __restrict__ xp) {
    int bhh = blockIdx.x;                        // b*58 + hh
    int b = bhh / 58, hh = bhh % 58;
    int t = threadIdx.x;
    char* blob = (char*)(xp + (size_t)bhh * 8192);
    if (hh == 0 || hh == 57) {
        u16x8 z = {0, 0, 0, 0, 0, 0, 0, 0};
#pragma unroll
        for (int i = 0; i < 4; ++i)
            *(u16x8*)(blob + (i * 256 + t) * 16) = z;
        return;
    }
    int h = hh - 1;
    float xz = *xzp;
    const float* xb = x + (size_t)b * 128 * 3136 + h * 56;   // + c*3136 + w
#pragma unroll
    for (int i = 0; i < 4; ++i) {
        int chunk = i * 256 + t;                 // 0..1023
        int byte = chunk * 16;
        int w = byte >> 8;                       // 0..63
        int slot = byte & 255;
        int c2 = slot ^ ((w & 7) << 4);          // un-swizzle -> source c
        int c0 = c2 >> 1;
        int wsrc = w - 1;
        bool valid = (unsigned)wsrc < 56u;
        u16x8 v;
#pragma unroll
        for (int j = 0; j < 8; ++j) {
            float f = valid ? (xb[(size_t)(c0 + j) * 3136 + wsrc] - xz) : 0.0f;
            v[j] = (unsigned short)(__float_as_uint(f) >> 16);
        }
        *(u16x8*)(blob + byte) = v;
    }
}

// ---- main conv ----
__global__ __launch_bounds__(512, 2)
void conv_kernel(const unsigned short* __restrict__ wt2,
                 const unsigned short* __restrict__ xp,
                 const float* __restrict__ bias,
                 const float* __restrict__ Mp,
                 const float* __restrict__ yzp,
                 float* __restrict__ out) {
    __shared__ __align__(1024) char smem[131072];    // A 96KB + B dbuf 2x16KB
    char* As = smem;
    char* Bs = smem + 98304;

    const int tid = threadIdx.x;
    const int lane = tid & 63;
    const int wid = tid >> 6;                        // 0..7
    const int l15 = lane & 15, lg = lane >> 4;
    const int wm = wid >> 2;                         // 0..1: which h-row pair
    const int wn = wid & 3;                          // 0..3: which 64-cout slice
    const int bx = blockIdx.x;                       // b*14 + h-group
    const int b = bx / 14;
    const int h0 = (bx % 14) * 4;                    // 4 output rows per block

    // ---- prologue: A = 6 row-blobs (96KB); B stage 0 into slot 0 ----
    const char* agbase = (const char*)xp + (size_t)(b * 58 + h0) * 16384;
    const char* wgbase = (const char*)wt2;
#pragma unroll
    for (int i = 0; i < 12; ++i) {
        int off = i * 8192 + wid * 1024;
        gload_lds16(agbase + off + lane * 16, As + off);
    }
    {
        const char* src = wgbase;
        gload_lds16(src + wid * 1024 + lane * 16, Bs + wid * 1024);
        gload_lds16(src + 8192 + wid * 1024 + lane * 16, Bs + 8192 + wid * 1024);
    }

    f32x4 acc[8][4];
#pragma unroll
    for (int i = 0; i < 8; ++i)
#pragma unroll
        for (int j = 0; j < 4; ++j)
            acc[i][j] = (f32x4){0.f, 0.f, 0.f, 0.f};

    __syncthreads();                                 // A + B0 staged

#pragma unroll
    for (int kh = 0; kh < 3; ++kh) {
#pragma unroll
        for (int kw = 0; kw < 3; ++kw) {
#pragma unroll
            for (int kc = 0; kc < 4; ++kc) {
                const int sidx = (kh * 3 + kw) * 4 + kc;     // compile-time
                const int bslot = (sidx & 1) * 16384;
                // ---- 1) ALL fragment reads first ----
                bf16x8 bfr[4];
#pragma unroll
                for (int fn = 0; fn < 4; ++fn) {
                    int rr = fn * 16 + l15;
                    int bbyte = bslot + (wn >> 1) * 8192 + rr * 128 +
                                (((wn & 1) * 64 + lg * 16) ^ ((rr & 7) << 4));
                    bfr[fn] = *(const bf16x8*)(Bs + bbyte);
                }
                bf16x8 afr[8];
#pragma unroll
                for (int fm = 0; fm < 8; ++fm) {
                    int w = (fm & 3) * 16 + l15 + kw;
                    int wc = w > 63 ? 63 : w;        // clamped lanes are dead outputs
                    int row = wm * 2 + (fm >> 2) + kh;
                    int abyte = row * 16384 + wc * 256 +
                                ((kc * 64 + lg * 16) ^ ((wc & 7) << 4));
                    afr[fm] = *(const bf16x8*)(As + abyte);
                }
                // ---- 2) THEN issue next B prefetch (other slot) ----
                if (sidx < 35) {
                    const char* src = wgbase + (size_t)(sidx + 1) * 16384;
                    char* dst = Bs + ((sidx + 1) & 1) * 16384;
                    gload_lds16(src + wid * 1024 + lane * 16, dst + wid * 1024);
                    gload_lds16(src + 8192 + wid * 1024 + lane * 16,
                                dst + 8192 + wid * 1024);
                }
                // ---- 3) MFMA burst ----
#pragma unroll
                for (int fm = 0; fm < 8; ++fm)
#pragma unroll
                    for (int fn = 0; fn < 4; ++fn)
                        acc[fm][fn] = __builtin_amdgcn_mfma_f32_16x16x32_bf16(
                            afr[fm], bfr[fn], acc[fm][fn], 0, 0, 0);
                __syncthreads();                     // drain prefetch + WAR guard
            }
        }
    }

    // ---- epilogue: requantize + ReLU + round ----
    const float Mv = *Mp;
    const float yzv = *yzp;
#pragma unroll
    for (int fn = 0; fn < 4; ++fn) {
        const int cout = wn * 64 + fn * 16 + l15;
        const float bv = bias[cout];
#pragma unroll
        for (int fm = 0; fm < 8; ++fm) {
            const int h = h0 + wm * 2 + (fm >> 2);
            const size_t rowb = ((size_t)(b * 256 + cout) * 56 + h) * 56;
#pragma unroll
            for (int reg = 0; reg < 4; ++reg) {
                int w = (fm & 3) * 16 + lg * 4 + reg;
                if (w < 56) {
                    float v = (acc[fm][fn][reg] + bv) * Mv + yzv;
                    v = fmaxf(v, yzv);
                    out[rowb + w] = rintf(v);
                }
            }
        }
    }
}

extern "C" void kernel_launch(void* const* d_in, const int* in_sizes, int n_in,
                              void* d_out, int out_size, void* d_ws, size_t ws_size,
                              hipStream_t stream) {
    const float* x    = (const float*)d_in[0];
    const float* w    = (const float*)d_in[1];
    const float* bias = (const float*)d_in[2];
    const float* Mp   = (const float*)d_in[3];
    const float* xzp  = (const float*)d_in[4];
    const float* wzp  = (const float*)d_in[5];
    const float* yzp  = (const float*)d_in[6];
    float* out = (float*)d_out;

    unsigned short* wt2 = (unsigned short*)d_ws;           // 576 KB
    unsigned short* xp  = wt2 + WT2_ELEMS;                 // ~30.4 MB

    wprep_kernel<<<WT2_ELEMS / 256, 256, 0, stream>>>(w, wzp, wt2);
    xprep_kernel<<<32 * 58, 256, 0, stream>>>(x, xzp, xp);

    conv_kernel<<<32 * 14, 512, 0, stream>>>(wt2, xp, bias, Mp, yzp, out);
}

// Round 11
// 113.311 us; speedup vs baseline: 1.1954x; 1.1662x over previous
//
#include <hip/hip_runtime.h>
#include <hip/hip_bf16.h>

// Quantized 3x3 conv via int8 implicit GEMM.
// B=32, Cin=128, Cout=256, H=W=56, pad=1. M = b,h,w(64pad), N=256, K = 9 taps x 128 cin.
//
// Exact integer factorization (pads contribute 0, matching pad-after-sub):
//   (x - xz)(w - wz) = xi*wi + (128 - wz)*xi,   xi = x - rint(xz) (in [-128,127]),
//   wi = w - 128 (always in [-128,127]).
//   acc_true = i8gemm(xi, wi) + (128 - wz) * S,  S = sum_window(xi).
//
// xpi8 blob per (b,hh): 64 w x 128 c bytes: byte(w,c) = w*128 + (c ^ ((w&7)<<4)).
// wti8 blob per (r,ch): 64 rows x 256B, row rr holds n in {rr, rr+64, rr+128, rr+192}:
//   byte(n,kl) = (n&63)*256 + (((n>>6)*64 + kl) ^ (((n&63)&7)<<4)), kl in [0,64).
// Swizzles are involutions; conv stages with global_load_lds (LINEAR dest) and
// reads with the same XOR (rule #21). Both frag reads are 2-way (free).
//
// conv: 256 thr / 4 waves (1m x 4n), block tile 64m(1 h-row) x 256n, per-wave
// 64m x 64n (acc i32x4[4][4]); A resident 24KB, B dbuf 2x16KB; LDS 56KB ->
// 2 blocks/CU so same-SIMD waves come from DIFFERENT blocks (true overlap).
// K-step = 64 (i8 MFMA K=64): 18 steps, R6-proven prefetch-first order.

typedef __attribute__((ext_vector_type(4))) int   i32x4;
typedef __attribute__((ext_vector_type(4))) float f32x4;

#define WTI8_BYTES (18 * 16384)            // 294,912
#define XPI8_BYTES (32 * 58 * 8192)        // 15,204,352
#define COLSUM_ELEMS (32 * 58 * 64)        // int32

__device__ __forceinline__ void gload_lds16(const void* g, void* l) {
    __builtin_amdgcn_global_load_lds(
        (const __attribute__((address_space(1))) void*)g,
        (__attribute__((address_space(3))) void*)l, 16, 0, 0);
}

// ---- weight prep: w[cout][cin][3][3] - 128 -> wti8 blobs (swizzle-baked) ----
__global__ void wprep_kernel(const float* __restrict__ w, char* __restrict__ wt) {
    int cidx = blockIdx.x * 256 + threadIdx.x;   // 16B chunk id, < 18432
    int blob = cidx >> 10;                       // r*2 + ch
    int e    = cidx & 1023;
    int byte0 = e * 16;
    int rr  = byte0 >> 8;                        // row 0..63
    int off = byte0 & 255;                       // 16-aligned
    int src = off ^ ((rr & 7) << 4);             // un-swizzle (16B-block safe)
    int q   = src >> 6;                          // n>>6
    int kl0 = src & 63;                          // 16-aligned
    int r = blob >> 1, ch = blob & 1;
    int n = q * 64 + rr;
    union { char c[16]; i32x4 v; } u;
#pragma unroll
    for (int j = 0; j < 16; ++j) {
        int cin = ch * 64 + kl0 + j;
        u.c[j] = (char)((int)w[(size_t)n * 1152 + cin * 9 + r] - 128);
    }
    *(i32x4*)(wt + (size_t)blob * 16384 + byte0) = u.v;
}

// ---- x prep: NCHW fp32 -> swizzled padded NHWC int8 + per-position colsum ----
__global__ void xprep_kernel(const float* __restrict__ x, const float* __restrict__ xzp,
                             char* __restrict__ xpi8, int* __restrict__ colsum) {
    int bhh = blockIdx.x;                        // b*58 + hh
    int b = bhh / 58, hh = bhh % 58;
    int t = threadIdx.x;
    char* blob = xpi8 + (size_t)bhh * 8192;
    int w = t >> 2;                              // 0..63 (4 threads per w)
    if (hh == 0 || hh == 57) {
        i32x4 z = {0, 0, 0, 0};
        *(i32x4*)(blob + t * 32)      = z;
        *(i32x4*)(blob + t * 32 + 16) = z;
        if ((t & 3) == 0) colsum[bhh * 64 + w] = 0;
        return;
    }
    const int ZX = (int)rintf(*xzp);             // 128 -> xi fits int8
    const float* xb = x + (size_t)b * 128 * 3136 + (hh - 1) * 56;
    bool valid = (w >= 1 && w <= 56);
    int wi = w - 1;
    int csum = 0;
#pragma unroll
    for (int cc = 0; cc < 2; ++cc) {
        int s8 = (t & 3) * 2 + cc;               // 0..7
        int c0 = (s8 * 16) ^ ((w & 7) << 4);     // un-swizzled source c base
        union { char c[16]; i32x4 v; } u;
#pragma unroll
        for (int j = 0; j < 16; ++j) {
            int val = 0;
            if (valid) val = (int)xb[(size_t)(c0 + j) * 3136 + wi] - ZX;
            u.c[j] = (char)val;
            csum += val;
        }
        *(i32x4*)(blob + w * 128 + s8 * 16) = u.v;
    }
    csum += __shfl_xor(csum, 1);
    csum += __shfl_xor(csum, 2);
    if ((t & 3) == 0) colsum[bhh * 64 + w] = csum;
}

// ---- main conv: int8 implicit GEMM ----
__global__ __launch_bounds__(256, 2)
void conv_kernel(const char* __restrict__ wt,
                 const char* __restrict__ xpi8,
                 const int* __restrict__ colsum,
                 const float* __restrict__ bias,
                 const float* __restrict__ Mp,
                 const float* __restrict__ wzp,
                 const float* __restrict__ yzp,
                 float* __restrict__ out) {
    __shared__ __align__(1024) char smem[57344];   // A 24KB + B dbuf 2x16KB
    __shared__ int s2row[64];
    char* As = smem;
    char* Bs = smem + 24576;

    const int tid = threadIdx.x;
    const int lane = tid & 63;
    const int wn = tid >> 6;                       // 0..3: 64-cout slice
    const int l15 = lane & 15, lg = lane >> 4;
    const int bx = blockIdx.x;                     // b*56 + h
    const int b = bx / 56;
    const int h = bx % 56;

    // ---- prologue: A = 3 row-blobs (24KB); B stage 0 (16KB); S2 row ----
    const char* agbase = xpi8 + (size_t)(b * 58 + h) * 8192;
#pragma unroll
    for (int i = 0; i < 6; ++i)
        gload_lds16(agbase + i * 4096 + tid * 16, As + i * 4096 + tid * 16);
#pragma unroll
    for (int i = 0; i < 4; ++i)
        gload_lds16(wt + i * 4096 + tid * 16, Bs + i * 4096 + tid * 16);
    if (tid < 64) {
        int s = 0;
        if (tid < 56) {
#pragma unroll
            for (int kh = 0; kh < 3; ++kh)
#pragma unroll
                for (int kw = 0; kw < 3; ++kw)
                    s += colsum[(b * 58 + h + kh) * 64 + tid + kw];
        }
        s2row[tid] = s;
    }

    i32x4 acc[4][4];
#pragma unroll
    for (int i = 0; i < 4; ++i)
#pragma unroll
        for (int j = 0; j < 4; ++j)
            acc[i][j] = (i32x4){0, 0, 0, 0};

    __syncthreads();                               // A + B0 + s2row ready

#pragma unroll
    for (int s = 0; s < 18; ++s) {                 // 9 taps x 2 cin-halves
        // prefetch next B blob into the other slot (issue-early, R6-proven)
        if (s < 17) {
            const char* src = wt + (size_t)(s + 1) * 16384;
            char* dst = Bs + ((s + 1) & 1) * 16384;
#pragma unroll
            for (int i = 0; i < 4; ++i)
                gload_lds16(src + i * 4096 + tid * 16, dst + i * 4096 + tid * 16);
        }
        const int kh = (s >> 1) / 3, kw = (s >> 1) % 3, ch = s & 1;
        // B fragments (4 x 16n)
        i32x4 bfr[4];
#pragma unroll
        for (int fn = 0; fn < 4; ++fn) {
            int rr = fn * 16 + l15;
            int bb = (s & 1) * 16384 + rr * 256 +
                     ((wn * 64 + lg * 16) ^ ((rr & 7) << 4));
            bfr[fn] = *(const i32x4*)(Bs + bb);
        }
        // A fragments (4 x 16m), kw-shifted swizzled read
        i32x4 afr[4];
#pragma unroll
        for (int fm = 0; fm < 4; ++fm) {
            int wv = fm * 16 + l15 + kw;
            int wc = wv > 63 ? 63 : wv;            // clamped lanes are dead outputs
            int ab = kh * 8192 + wc * 128 +
                     ((ch * 64 + lg * 16) ^ ((wc & 7) << 4));
            afr[fm] = *(const i32x4*)(As + ab);
        }
#pragma unroll
        for (int fm = 0; fm < 4; ++fm)
#pragma unroll
            for (int fn = 0; fn < 4; ++fn)
                acc[fm][fn] = __builtin_amdgcn_mfma_i32_16x16x64_i8(
                    afr[fm], bfr[fn], acc[fm][fn], 0, 0, 0);
        __syncthreads();                           // drain prefetch + WAR guard
    }

    // ---- epilogue: +correction, requantize, ReLU, round ----
    const float Mv  = *Mp;
    const float yzv = *yzp;
    const float CWf = 128.0f - *wzp;               // (128 - w_zero)
#pragma unroll
    for (int fn = 0; fn < 4; ++fn) {
        const int cout = wn * 64 + fn * 16 + l15;
        const float bv = bias[cout];
        const size_t rowb = ((size_t)(b * 256 + cout) * 56 + h) * 56;
#pragma unroll
        for (int fm = 0; fm < 4; ++fm) {
#pragma unroll
            for (int reg = 0; reg < 4; ++reg) {
                int m = fm * 16 + lg * 4 + reg;
                if (m < 56) {
                    float af = (float)acc[fm][fn][reg] + CWf * (float)s2row[m];
                    float v = (af + bv) * Mv + yzv;
                    v = fmaxf(v, yzv);
                    out[rowb + m] = rintf(v);
                }
            }
        }
    }
}

extern "C" void kernel_launch(void* const* d_in, const int* in_sizes, int n_in,
                              void* d_out, int out_size, void* d_ws, size_t ws_size,
                              hipStream_t stream) {
    const float* x    = (const float*)d_in[0];
    const float* w    = (const float*)d_in[1];
    const float* bias = (const float*)d_in[2];
    const float* Mp   = (const float*)d_in[3];
    const float* xzp  = (const float*)d_in[4];
    const float* wzp  = (const float*)d_in[5];
    const float* yzp  = (const float*)d_in[6];
    float* out = (float*)d_out;

    char* wt     = (char*)d_ws;                          // 288 KB
    char* xpi8   = wt + WTI8_BYTES;                      // 15.2 MB
    int*  colsum = (int*)(xpi8 + XPI8_BYTES);            // 475 KB

    wprep_kernel<<<72, 256, 0, stream>>>(w, wt);
    xprep_kernel<<<32 * 58, 256, 0, stream>>>(x, xzp, xpi8, colsum);
    conv_kernel<<<32 * 56, 256, 0, stream>>>(wt, xpi8, colsum, bias, Mp, wzp, yzp, out);
}

// Round 12
// 112.385 us; speedup vs baseline: 1.2053x; 1.0082x over previous
//
#include <hip/hip_runtime.h>
#include <hip/hip_bf16.h>

// Quantized 3x3 conv via int8 implicit GEMM — barrier-free K-loop.
// B=32, Cin=128, Cout=256, H=W=56, pad=1. M=(b,h,w64), N=256, K=9x128.
//
// (x-xz)(w-wz) = xi*wi + (128-wz)*xi,  xi=x-128 (int8), wi=w-128 (int8);
// acc = i8gemm + (128-wz)*S,  S = window-sum of xi (pads contribute 0).
//
// xpi8 blob per (b,hh), 8KB: byte(w,c) = w*128 + (c ^ ((w&7)<<4))  (A swizzle
// for LDS-read; staged linearly by global_load_lds, read with same XOR).
// wt blob per (r,ch), 16KB, PLAIN layout (B is read direct global->reg):
//   byte = (n&63)*256 + (n>>6)*64 + kl,  kl in [0,64), value = w-128.
//
// conv: 256 thr / 4 waves (1m x 4n), tile 64m(1 h-row) x 256n; per-wave
// 64x64, acc i32x4[4][4]. A resident in LDS (24KB, staged once);
// B frags via global_load_dwordx4 from L2-resident 288KB weight array.
// ONE barrier total (after prologue) -> no per-step vmcnt(0)/barrier tax;
// 3 blocks/CU (12 waves) + compiler pipelining overlap loads with MFMA.

typedef __attribute__((ext_vector_type(4))) int   i32x4;
typedef __attribute__((ext_vector_type(4))) float f32x4;

#define WTI8_BYTES (18 * 16384)            // 294,912
#define XPI8_BYTES (32 * 58 * 8192)        // 15,204,352

__device__ __forceinline__ void gload_lds16(const void* g, void* l) {
    __builtin_amdgcn_global_load_lds(
        (const __attribute__((address_space(1))) void*)g,
        (__attribute__((address_space(3))) void*)l, 16, 0, 0);
}

// ---- weight prep: w[cout][cin][3][3] - 128 -> plain wt blobs ----
__global__ void wprep_kernel(const float* __restrict__ w, char* __restrict__ wt) {
    int cidx = blockIdx.x * 256 + threadIdx.x;   // 16B chunk id, < 18432
    int blob = cidx >> 10;                       // r*2 + ch
    int e    = cidx & 1023;
    int byte0 = e * 16;
    int rr  = byte0 >> 8;                        // row 0..63
    int off = byte0 & 255;
    int q   = off >> 6;                          // n>>6
    int kl0 = off & 63;                          // 16-aligned
    int r = blob >> 1, ch = blob & 1;
    int n = q * 64 + rr;
    union { char c[16]; i32x4 v; } u;
#pragma unroll
    for (int j = 0; j < 16; ++j) {
        int cin = ch * 64 + kl0 + j;
        u.c[j] = (char)((int)w[(size_t)n * 1152 + cin * 9 + r] - 128);
    }
    *(i32x4*)(wt + (size_t)blob * 16384 + byte0) = u.v;
}

// ---- x prep: coalesced NCHW read -> swizzled padded NHWC int8 + colsum ----
__global__ void xprep_kernel(const float* __restrict__ x, const float* __restrict__ xzp,
                             char* __restrict__ xpi8, int* __restrict__ colsum) {
    int bhh = blockIdx.x;                        // b*58 + hh
    int b = bhh / 58, hh = bhh % 58;
    int tid = threadIdx.x;
    char* blob = xpi8 + (size_t)bhh * 8192;
    int w  = tid & 63;                           // padded col (lane = w: coalesced)
    int cq = tid >> 6;                           // 0..3, 32 cin each
    __shared__ int ps[4][64];
    if (hh == 0 || hh == 57) {
        i32x4 z = {0, 0, 0, 0};
        *(i32x4*)(blob + tid * 32)      = z;
        *(i32x4*)(blob + tid * 32 + 16) = z;
        if (cq == 0) colsum[bhh * 64 + w] = 0;
        return;
    }
    const int ZX = (int)rintf(*xzp);             // 128
    bool valid = (w >= 1 && w <= 56);
    const float* xb = x + (size_t)b * 128 * 3136 + (size_t)(hh - 1) * 56 +
                      (valid ? (w - 1) : 0);
    int csum = 0;
#pragma unroll
    for (int u = 0; u < 2; ++u) {
        union { char c[16]; i32x4 v; } uu;
#pragma unroll
        for (int j = 0; j < 16; ++j) {
            int c = cq * 32 + u * 16 + j;
            int val = valid ? ((int)xb[(size_t)c * 3136] - ZX) : 0;
            uu.c[j] = (char)val;
            csum += val;
        }
        *(i32x4*)(blob + w * 128 + ((cq * 32 + u * 16) ^ ((w & 7) << 4))) = uu.v;
    }
    ps[cq][w] = csum;
    __syncthreads();
    if (cq == 0)
        colsum[bhh * 64 + w] = ps[0][w] + ps[1][w] + ps[2][w] + ps[3][w];
}

// ---- main conv: barrier-free int8 implicit GEMM ----
__global__ __launch_bounds__(256, 3)
void conv_kernel(const char* __restrict__ wt,
                 const char* __restrict__ xpi8,
                 const int* __restrict__ colsum,
                 const float* __restrict__ bias,
                 const float* __restrict__ Mp,
                 const float* __restrict__ wzp,
                 const float* __restrict__ yzp,
                 float* __restrict__ out) {
    __shared__ __align__(1024) char As[24576];     // A resident (3 row-blobs)
    __shared__ int s2row[64];

    const int tid = threadIdx.x;
    const int lane = tid & 63;
    const int wn = tid >> 6;                       // 0..3: 64-cout slice
    const int l15 = lane & 15, lg = lane >> 4;
    const int bx = blockIdx.x;                     // b*56 + h
    const int b = bx / 56;
    const int h = bx % 56;

    // ---- prologue: stage A (24KB) once; window colsum row ----
    const char* agbase = xpi8 + (size_t)(b * 58 + h) * 8192;
#pragma unroll
    for (int i = 0; i < 6; ++i)
        gload_lds16(agbase + i * 4096 + tid * 16, As + i * 4096 + tid * 16);
    if (tid < 64) {
        int s = 0;
        if (tid < 56) {
#pragma unroll
            for (int kh = 0; kh < 3; ++kh)
#pragma unroll
                for (int kw = 0; kw < 3; ++kw)
                    s += colsum[(b * 58 + h + kh) * 64 + tid + kw];
        }
        s2row[tid] = s;
    }

    i32x4 acc[4][4];
#pragma unroll
    for (int i = 0; i < 4; ++i)
#pragma unroll
        for (int j = 0; j < 4; ++j)
            acc[i][j] = (i32x4){0, 0, 0, 0};

    __syncthreads();                               // the ONLY barrier

#pragma unroll
    for (int s = 0; s < 18; ++s) {                 // 9 taps x 2 cin-halves
        const int kh = (s >> 1) / 3, kw = (s >> 1) % 3, ch = s & 1;
        // B fragments: direct global->reg (L2-resident weights)
        const char* bsrc = wt + (size_t)s * 16384 + wn * 64 + lg * 16;
        i32x4 bfr[4];
#pragma unroll
        for (int fn = 0; fn < 4; ++fn)
            bfr[fn] = *(const i32x4*)(bsrc + (fn * 16 + l15) * 256);
        // A fragments from LDS (kw-shifted, swizzled)
        i32x4 afr[4];
#pragma unroll
        for (int fm = 0; fm < 4; ++fm) {
            int wv = fm * 16 + l15 + kw;
            int wc = wv > 63 ? 63 : wv;            // clamped lanes are dead outputs
            int ab = kh * 8192 + wc * 128 +
                     ((ch * 64 + lg * 16) ^ ((wc & 7) << 4));
            afr[fm] = *(const i32x4*)(As + ab);
        }
#pragma unroll
        for (int fm = 0; fm < 4; ++fm)
#pragma unroll
            for (int fn = 0; fn < 4; ++fn)
                acc[fm][fn] = __builtin_amdgcn_mfma_i32_16x16x64_i8(
                    afr[fm], bfr[fn], acc[fm][fn], 0, 0, 0);
    }

    // ---- epilogue: +correction, requantize, ReLU, round ----
    const float Mv  = *Mp;
    const float yzv = *yzp;
    const float CWf = 128.0f - *wzp;               // (128 - w_zero)
#pragma unroll
    for (int fn = 0; fn < 4; ++fn) {
        const int cout = wn * 64 + fn * 16 + l15;
        const float bv = bias[cout];
        const size_t rowb = ((size_t)(b * 256 + cout) * 56 + h) * 56;
#pragma unroll
        for (int fm = 0; fm < 4; ++fm) {
#pragma unroll
            for (int reg = 0; reg < 4; ++reg) {
                int m = fm * 16 + lg * 4 + reg;
                if (m < 56) {
                    float af = (float)acc[fm][fn][reg] + CWf * (float)s2row[m];
                    float v = (af + bv) * Mv + yzv;
                    v = fmaxf(v, yzv);
                    out[rowb + m] = rintf(v);
                }
            }
        }
    }
}

extern "C" void kernel_launch(void* const* d_in, const int* in_sizes, int n_in,
                              void* d_out, int out_size, void* d_ws, size_t ws_size,
                              hipStream_t stream) {
    const float* x    = (const float*)d_in[0];
    const float* w    = (const float*)d_in[1];
    const float* bias = (const float*)d_in[2];
    const float* Mp   = (const float*)d_in[3];
    const float* xzp  = (const float*)d_in[4];
    const float* wzp  = (const float*)d_in[5];
    const float* yzp  = (const float*)d_in[6];
    float* out = (float*)d_out;

    char* wt     = (char*)d_ws;                          // 288 KB
    char* xpi8   = wt + WTI8_BYTES;                      // 15.2 MB
    int*  colsum = (int*)(xpi8 + XPI8_BYTES);            // 475 KB

    wprep_kernel<<<72, 256, 0, stream>>>(w, wt);
    xprep_kernel<<<32 * 58, 256, 0, stream>>>(x, xzp, xpi8, colsum);
    conv_kernel<<<32 * 56, 256, 0, stream>>>(wt, xpi8, colsum, bias, Mp, wzp, yzp, out);
}

// Round 13
// 96.302 us; speedup vs baseline: 1.4066x; 1.1670x over previous
//
#include <hip/hip_runtime.h>
#include <hip/hip_bf16.h>

// Quantized 3x3 conv via int8 implicit GEMM (R11 structure + transposed-D
// epilogue for coalesced stores).
// B=32, Cin=128, Cout=256, H=W=56, pad=1. M=(b,h,w64), N=256, K=9x128.
//
// (x-xz)(w-wz) = xi*wi + (128-wz)*xi,  xi=x-128 (int8), wi=w-128 (int8);
// acc = i8gemm + (128-wz)*S,  S = window-sum of xi (pads contribute 0).
//
// xpi8 blob per (b,hh), 8KB: byte(w,c) = w*128 + (c ^ ((w&7)<<4)).
// wti8 blob per (r,ch), 16KB: byte(n,kl) = (n&63)*256 +
//   (((n>>6)*64 + kl) ^ (((n&63)&7)<<4)), kl in [0,64).
// Swizzles are involutions; conv stages with global_load_lds (LINEAR dest)
// and reads with the same XOR (rule #21).
//
// KEY CHANGE vs R11: MFMA operands SWAPPED -> D is computed transposed:
//   acc[fn][fm]: row = cout_local = lg*4+reg, col = m = l15.
// Both operands of 16x16xK MFMA share the same fragment mapping
// (free = lane&15, k-chunk = lane>>4), so the same LDS fragments feed the
// swapped call. Epilogue stores become lane-contiguous in m (64B segments)
// instead of 16B-sparse scatter across 16 cout rows (the hidden ~40µs tax
// common to all prior rounds).

typedef __attribute__((ext_vector_type(4))) int   i32x4;
typedef __attribute__((ext_vector_type(4))) float f32x4;

#define WTI8_BYTES (18 * 16384)            // 294,912
#define XPI8_BYTES (32 * 58 * 8192)        // 15,204,352

__device__ __forceinline__ void gload_lds16(const void* g, void* l) {
    __builtin_amdgcn_global_load_lds(
        (const __attribute__((address_space(1))) void*)g,
        (__attribute__((address_space(3))) void*)l, 16, 0, 0);
}

// ---- weight prep: w[cout][cin][3][3] - 128 -> wti8 blobs (swizzle-baked) ----
__global__ void wprep_kernel(const float* __restrict__ w, char* __restrict__ wt) {
    int cidx = blockIdx.x * 256 + threadIdx.x;   // 16B chunk id, < 18432
    int blob = cidx >> 10;                       // r*2 + ch
    int e    = cidx & 1023;
    int byte0 = e * 16;
    int rr  = byte0 >> 8;                        // row 0..63
    int off = byte0 & 255;                       // 16-aligned
    int src = off ^ ((rr & 7) << 4);             // un-swizzle (16B-block safe)
    int q   = src >> 6;                          // n>>6
    int kl0 = src & 63;                          // 16-aligned
    int r = blob >> 1, ch = blob & 1;
    int n = q * 64 + rr;
    union { char c[16]; i32x4 v; } u;
#pragma unroll
    for (int j = 0; j < 16; ++j) {
        int cin = ch * 64 + kl0 + j;
        u.c[j] = (char)((int)w[(size_t)n * 1152 + cin * 9 + r] - 128);
    }
    *(i32x4*)(wt + (size_t)blob * 16384 + byte0) = u.v;
}

// ---- x prep: coalesced NCHW read -> swizzled padded NHWC int8 + colsum ----
__global__ void xprep_kernel(const float* __restrict__ x, const float* __restrict__ xzp,
                             char* __restrict__ xpi8, int* __restrict__ colsum) {
    int bhh = blockIdx.x;                        // b*58 + hh
    int b = bhh / 58, hh = bhh % 58;
    int tid = threadIdx.x;
    char* blob = xpi8 + (size_t)bhh * 8192;
    int w  = tid & 63;                           // padded col (lane = w: coalesced)
    int cq = tid >> 6;                           // 0..3, 32 cin each
    __shared__ int ps[4][64];
    if (hh == 0 || hh == 57) {
        i32x4 z = {0, 0, 0, 0};
        *(i32x4*)(blob + tid * 32)      = z;
        *(i32x4*)(blob + tid * 32 + 16) = z;
        if (cq == 0) colsum[bhh * 64 + w] = 0;
        return;
    }
    const int ZX = (int)rintf(*xzp);             // 128
    bool valid = (w >= 1 && w <= 56);
    const float* xb = x + (size_t)b * 128 * 3136 + (size_t)(hh - 1) * 56 +
                      (valid ? (w - 1) : 0);
    int csum = 0;
#pragma unroll
    for (int u = 0; u < 2; ++u) {
        union { char c[16]; i32x4 v; } uu;
#pragma unroll
        for (int j = 0; j < 16; ++j) {
            int c = cq * 32 + u * 16 + j;
            int val = valid ? ((int)xb[(size_t)c * 3136] - ZX) : 0;
            uu.c[j] = (char)val;
            csum += val;
        }
        *(i32x4*)(blob + w * 128 + ((cq * 32 + u * 16) ^ ((w & 7) << 4))) = uu.v;
    }
    ps[cq][w] = csum;
    __syncthreads();
    if (cq == 0)
        colsum[bhh * 64 + w] = ps[0][w] + ps[1][w] + ps[2][w] + ps[3][w];
}

// ---- main conv: int8 implicit GEMM, transposed-D epilogue ----
__global__ __launch_bounds__(256, 2)
void conv_kernel(const char* __restrict__ wt,
                 const char* __restrict__ xpi8,
                 const int* __restrict__ colsum,
                 const float* __restrict__ bias,
                 const float* __restrict__ Mp,
                 const float* __restrict__ wzp,
                 const float* __restrict__ yzp,
                 float* __restrict__ out) {
    __shared__ __align__(1024) char smem[57344];   // A 24KB + B dbuf 2x16KB
    __shared__ int s2row[64];
    char* As = smem;
    char* Bs = smem + 24576;

    const int tid = threadIdx.x;
    const int lane = tid & 63;
    const int wn = tid >> 6;                       // 0..3: 64-cout slice
    const int l15 = lane & 15, lg = lane >> 4;
    const int bx = blockIdx.x;                     // b*56 + h
    const int b = bx / 56;
    const int h = bx % 56;

    // ---- prologue: A = 3 row-blobs (24KB); B stage 0 (16KB); S2 row ----
    const char* agbase = xpi8 + (size_t)(b * 58 + h) * 8192;
#pragma unroll
    for (int i = 0; i < 6; ++i)
        gload_lds16(agbase + i * 4096 + tid * 16, As + i * 4096 + tid * 16);
#pragma unroll
    for (int i = 0; i < 4; ++i)
        gload_lds16(wt + i * 4096 + tid * 16, Bs + i * 4096 + tid * 16);
    if (tid < 64) {
        int s = 0;
        if (tid < 56) {
#pragma unroll
            for (int kh = 0; kh < 3; ++kh)
#pragma unroll
                for (int kw = 0; kw < 3; ++kw)
                    s += colsum[(b * 58 + h + kh) * 64 + tid + kw];
        }
        s2row[tid] = s;
    }

    i32x4 acc[4][4];                               // [fn][fm]: row=cout, col=m
#pragma unroll
    for (int i = 0; i < 4; ++i)
#pragma unroll
        for (int j = 0; j < 4; ++j)
            acc[i][j] = (i32x4){0, 0, 0, 0};

    __syncthreads();                               // A + B0 + s2row ready

#pragma unroll
    for (int s = 0; s < 18; ++s) {                 // 9 taps x 2 cin-halves
        // prefetch next B blob into the other slot (issue-early, R6-proven)
        if (s < 17) {
            const char* src = wt + (size_t)(s + 1) * 16384;
            char* dst = Bs + ((s + 1) & 1) * 16384;
#pragma unroll
            for (int i = 0; i < 4; ++i)
                gload_lds16(src + i * 4096 + tid * 16, dst + i * 4096 + tid * 16);
        }
        const int kh = (s >> 1) / 3, kw = (s >> 1) % 3, ch = s & 1;
        // B fragments (w): free = l15 (cout slice row), k-chunk = lg
        i32x4 bfr[4];
#pragma unroll
        for (int fn = 0; fn < 4; ++fn) {
            int rr = fn * 16 + l15;
            int bb = (s & 1) * 16384 + rr * 256 +
                     ((wn * 64 + lg * 16) ^ ((rr & 7) << 4));
            bfr[fn] = *(const i32x4*)(Bs + bb);
        }
        // A fragments (x): free = l15 (m), k-chunk = lg; kw-shifted swizzled
        i32x4 afr[4];
#pragma unroll
        for (int fm = 0; fm < 4; ++fm) {
            int wv = fm * 16 + l15 + kw;
            int wc = wv > 63 ? 63 : wv;            // clamped lanes are dead outputs
            int ab = kh * 8192 + wc * 128 +
                     ((ch * 64 + lg * 16) ^ ((wc & 7) << 4));
            afr[fm] = *(const i32x4*)(As + ab);
        }
        // SWAPPED operands: D[row=cout][col=m]
#pragma unroll
        for (int fn = 0; fn < 4; ++fn)
#pragma unroll
            for (int fm = 0; fm < 4; ++fm)
                acc[fn][fm] = __builtin_amdgcn_mfma_i32_16x16x64_i8(
                    bfr[fn], afr[fm], acc[fn][fm], 0, 0, 0);
        __syncthreads();                           // drain prefetch + WAR guard
    }

    // ---- epilogue: +correction, requantize, ReLU, round; coalesced in m ----
    const float Mv  = *Mp;
    const float yzv = *yzp;
    const float CWf = 128.0f - *wzp;               // (128 - w_zero)
#pragma unroll
    for (int fn = 0; fn < 4; ++fn) {
#pragma unroll
        for (int reg = 0; reg < 4; ++reg) {
            const int cout = wn * 64 + fn * 16 + lg * 4 + reg;
            const float bv = bias[cout];
            const size_t rowb = ((size_t)(b * 256 + cout) * 56 + h) * 56;
#pragma unroll
            for (int fm = 0; fm < 4; ++fm) {
                int m = fm * 16 + l15;             // lane-contiguous!
                if (m < 56) {
                    float af = (float)acc[fn][fm][reg] + CWf * (float)s2row[m];
                    float v = (af + bv) * Mv + yzv;
                    v = fmaxf(v, yzv);
                    out[rowb + m] = rintf(v);
                }
            }
        }
    }
}

extern "C" void kernel_launch(void* const* d_in, const int* in_sizes, int n_in,
                              void* d_out, int out_size, void* d_ws, size_t ws_size,
                              hipStream_t stream) {
    const float* x    = (const float*)d_in[0];
    const float* w    = (const float*)d_in[1];
    const float* bias = (const float*)d_in[2];
    const float* Mp   = (const float*)d_in[3];
    const float* xzp  = (const float*)d_in[4];
    const float* wzp  = (const float*)d_in[5];
    const float* yzp  = (const float*)d_in[6];
    float* out = (float*)d_out;

    char* wt     = (char*)d_ws;                          // 288 KB
    char* xpi8   = wt + WTI8_BYTES;                      // 15.2 MB
    int*  colsum = (int*)(xpi8 + XPI8_BYTES);            // 475 KB

    wprep_kernel<<<72, 256, 0, stream>>>(w, wt);
    xprep_kernel<<<32 * 58, 256, 0, stream>>>(x, xzp, xpi8, colsum);
    conv_kernel<<<32 * 56, 256, 0, stream>>>(wt, xpi8, colsum, bias, Mp, wzp, yzp, out);
}